// Round 12
// baseline (129.031 us; speedup 1.0000x reference)
//
#include <hip/hip_runtime.h>
#include <math.h>
#include <stdint.h>

typedef __bf16 bf16;
typedef __bf16 bf16x8 __attribute__((ext_vector_type(8)));
typedef __bf16 bf16x4 __attribute__((ext_vector_type(4)));
typedef float f32x4 __attribute__((ext_vector_type(4)));
typedef float f32x16 __attribute__((ext_vector_type(16)));
typedef unsigned int u32;

// element index into a [rows][64] bf16 tile, XOR-swizzled in 16B (8-elem) chunks
__device__ __forceinline__ int swz(int row, int chunk) {
    return row * 64 + ((chunk ^ (row & 7)) << 3);
}

// async 16B global->LDS; lds must be wave-uniform base (HW adds lane*16)
__device__ __forceinline__ void gld16(void* lds, const void* g) {
    __builtin_amdgcn_global_load_lds(
        (const __attribute__((address_space(1))) u32*)g,
        (__attribute__((address_space(3))) u32*)lds, 16, 0, 0);
}

__global__ void cast_bf16_k(const float* __restrict__ src, bf16* __restrict__ dst, int n) {
    const int stride = gridDim.x * blockDim.x * 4;
    for (int i = (blockIdx.x * blockDim.x + threadIdx.x) * 4; i < n; i += stride) {
        float4 v = *(const float4*)(src + i);
        bf16x4 o = {(bf16)v.x, (bf16)v.y, (bf16)v.z, (bf16)v.w};
        *(bf16x4*)(dst + i) = o;
    }
}

__global__ void cast3_bf16_k(const float* __restrict__ s0, bf16* __restrict__ d0,
                             const float* __restrict__ s1, bf16* __restrict__ d1,
                             const float* __restrict__ s2, bf16* __restrict__ d2, int n) {
    const int stride = gridDim.x * blockDim.x * 4;
    for (int i = (blockIdx.x * blockDim.x + threadIdx.x) * 4; i < n; i += stride) {
        float4 v0 = *(const float4*)(s0 + i);
        float4 v1 = *(const float4*)(s1 + i);
        float4 v2 = *(const float4*)(s2 + i);
        bf16x4 o0 = {(bf16)v0.x, (bf16)v0.y, (bf16)v0.z, (bf16)v0.w};
        bf16x4 o1 = {(bf16)v1.x, (bf16)v1.y, (bf16)v1.z, (bf16)v1.w};
        bf16x4 o2 = {(bf16)v2.x, (bf16)v2.y, (bf16)v2.z, (bf16)v2.w};
        *(bf16x4*)(d0 + i) = o0;
        *(bf16x4*)(d1 + i) = o1;
        *(bf16x4*)(d2 + i) = o2;
    }
}

// w2 [H][64][M] f32  ->  w2t [H][M][64] bf16
__global__ __launch_bounds__(256) void w2_transpose_k(const float* __restrict__ w2,
                                                      bf16* __restrict__ w2t, int M) {
    __shared__ float Tf[64][65];
    const int h = blockIdx.y, m0 = blockIdx.x * 64, t = threadIdx.x;
    {
        const int dr = t >> 4, c4 = (t & 15) * 4;
        #pragma unroll
        for (int it = 0; it < 4; ++it) {
            const int d = dr + it * 16;
            float4 v = *(const float4*)(w2 + ((size_t)h * 64 + d) * M + m0 + c4);
            Tf[d][c4] = v.x; Tf[d][c4 + 1] = v.y; Tf[d][c4 + 2] = v.z; Tf[d][c4 + 3] = v.w;
        }
    }
    __syncthreads();
    const int m = t >> 2;
    #pragma unroll
    for (int it = 0; it < 2; ++it) {
        const int ch = (t & 3) + it * 4;
        bf16x8 o;
        #pragma unroll
        for (int j = 0; j < 8; ++j) o[j] = (bf16)Tf[ch * 8 + j][m];
        *(bf16x8*)(w2t + ((size_t)h * M + m0 + m) * 64 + ch * 8) = o;
    }
}

// 128x128x64 bf16 MFMA GEMM (R9-verified: counted-vmcnt double buffer).
__global__ __launch_bounds__(256, 2) void gemm_bf16_k(const bf16* __restrict__ A,
                                                   const bf16* __restrict__ Bw,
                                                   const float* __restrict__ bias,
                                                   const float* __restrict__ bias2,
                                                   float* __restrict__ C0,
                                                   bf16* __restrict__ CK,
                                                   bf16* __restrict__ CV,
                                                   int M, int N, int K, int mode, int Ns)
{
    __shared__ __align__(16) bf16 As[2][128 * 64];
    __shared__ __align__(16) bf16 Bs[2][128 * 64];
    const int tid = threadIdx.x;
    const int w = tid >> 6, l = tid & 63;
    const int wr = w >> 1, wc = w & 1;
    const int lc = l & 15, lg = l >> 4;
    const int row0 = blockIdx.y * 128, col0 = blockIdx.x * 128;

    f32x4 acc[4][4] = {};

    const int nk = K >> 6;
    auto issue = [&](int buf, int k0) {
        #pragma unroll
        for (int i = 0; i < 4; ++i) {
            const int br = (w * 4 + i) * 8;
            const int r = br + (l >> 3);
            const int gs = (l & 7) ^ (r & 7);
            gld16(&As[buf][br * 64], A  + (size_t)(row0 + r) * K + k0 + gs * 8);
            gld16(&Bs[buf][br * 64], Bw + (size_t)(col0 + r) * K + k0 + gs * 8);
        }
    };

    issue(0, 0);
    int cur = 0;
    for (int kt = 0; kt < nk; ++kt) {
        if (kt + 1 < nk) {
            issue(cur ^ 1, (kt + 1) << 6);
            asm volatile("s_waitcnt vmcnt(8)" ::: "memory");
        } else {
            asm volatile("s_waitcnt vmcnt(0)" ::: "memory");
        }
        __builtin_amdgcn_s_barrier();
        #pragma unroll
        for (int ks = 0; ks < 2; ++ks) {
            bf16x8 af[4], bfv[4];
            #pragma unroll
            for (int i = 0; i < 4; ++i) {
                af[i]  = *(const bf16x8*)&As[cur][swz(wr * 64 + i * 16 + lc, ks * 4 + lg)];
                bfv[i] = *(const bf16x8*)&Bs[cur][swz(wc * 64 + i * 16 + lc, ks * 4 + lg)];
            }
            #pragma unroll
            for (int mi = 0; mi < 4; ++mi)
                #pragma unroll
                for (int ni = 0; ni < 4; ++ni)
                    acc[mi][ni] = __builtin_amdgcn_mfma_f32_16x16x32_bf16(af[mi], bfv[ni], acc[mi][ni], 0, 0, 0);
        }
        asm volatile("s_waitcnt lgkmcnt(0)" ::: "memory");
        __builtin_amdgcn_s_barrier();
        cur ^= 1;
    }

    #pragma unroll
    for (int ni = 0; ni < 4; ++ni) {
        const int col = col0 + wc * 64 + ni * 16 + lc;
        #pragma unroll
        for (int mi = 0; mi < 4; ++mi) {
            const int rowb = row0 + wr * 64 + mi * 16 + lg * 4;
            f32x4 v = acc[mi][ni];
            if (mode == 0) {
                const float bv = bias[col];
                #pragma unroll
                for (int r = 0; r < 4; ++r)
                    C0[(size_t)(rowb + r) * N + col] = v[r] + bv;
            } else if (col < Ns) {
                const float bv = bias[col];
                #pragma unroll
                for (int r = 0; r < 4; ++r)
                    CK[(size_t)(rowb + r) * Ns + col] = (bf16)fmaxf(v[r] + bv, 0.f);
            } else {
                const float bv = bias2[col - Ns];
                const int b = rowb >> 11, tt = rowb & 2047;   // T = 2048
                bf16x4 o = {(bf16)(v[0] + bv), (bf16)(v[1] + bv),
                            (bf16)(v[2] + bv), (bf16)(v[3] + bv)};
                *(bf16x4*)(CV + ((size_t)b * Ns + (col - Ns)) * 2048 + tt) = o;
            }
        }
    }
}

// v12: strip-decomposed causal attention. Each block = 4 waves x 32q (q-tile
// 128 rows at t*128) x a strip of <=8 s-tiles. Exact no-max softmax => strips
// are independent; partial O / row-sum accumulate via f32 atomicAdd into
// zeroed scratch; tiny normalize kernel finishes. Every wave active every
// iteration; 34KB LDS -> 4 blocks/CU resident, grid 1280 oversubscribed.
// Core tile math = v11-verified (frag-packed linear LDS, conflict-free).
__global__ __launch_bounds__(256, 4) void synth_attn_v12(const bf16* __restrict__ Kb,
                                                         const bf16* __restrict__ VT,
                                                         const bf16* __restrict__ w2t,
                                                         const float* __restrict__ b2,
                                                         float* __restrict__ Oacc,
                                                         float* __restrict__ Lacc)
{
    constexpr int T = 2048, C = 1024, M = 2048, H = 16;
    __shared__ __align__(16) bf16 ring[2][8192];   // per buf: W [0,4096), V [4096,8192)
    __shared__ float b2l[512];                     // strip's b2 slice
    const int tid = threadIdx.x;
    const int w = tid >> 6, l = tid & 63;
    const int c = l & 31, hi = l >> 5;

    // block -> (b, h, t128, strip): 40 strips per (b,h)
    const int bx = blockIdx.x;
    const int bh = bx / 40, u = bx % 40;
    int t, sp;
    if (u < 4)       { t = u;                sp = 0; }
    else if (u < 12) { t = 4 + ((u - 4) >> 1);  sp = (u - 4) & 1; }
    else if (u < 24) { t = 8 + (u - 12) / 3;    sp = (u - 12) % 3; }
    else             { t = 12 + ((u - 24) >> 2); sp = (u - 24) & 3; }
    const int h = bh & 15, b = bh >> 4;
    const int t0w = t * 128 + w * 32;          // wave's 32 q-rows
    const int myT = 2 * t + (w >> 1);          // wave's last (diagonal) s-tile
    const int sLo = sp * 8;
    const int nT = min(8, 2 * t + 2 - sLo);    // tiles in this strip (>=2)

    // b2 slice -> LDS (256 thr x 2 floats = 512)
    *(float2*)&b2l[tid * 2] = *(const float2*)(b2 + sp * 512 + tid * 2);
    asm volatile("s_waitcnt lgkmcnt(0)" ::: "memory");   // ds_write committed

    const bf16* Wg = w2t + (size_t)h * M * 64;            // [s][64] rows
    const bf16* Vg = VT + ((size_t)b * C + h * 64) * T;   // [d][T] rows

    // K fragments (B-operand of swapped QK): lane owns q=c, 4 k-slots of 16 d
    const bf16* Kg = Kb + ((size_t)(b * T + t0w + c)) * C + h * 64 + hi * 8;
    bf16x8 kf[4];
    #pragma unroll
    for (int kst = 0; kst < 4; ++kst) kf[kst] = *(const bf16x8*)(Kg + kst * 16);

    // stage s-tile sb into ring[buf]; wave stages W slots {2w,2w+1} and V
    // slots {2w,2w+1}: 4 gld16/wave/tile -> steady-state vmcnt(4).
    auto stage = [&](int buf, int sb) {
        bf16* dst = &ring[buf][0];
        const int s0 = sb * 64;
        #pragma unroll
        for (int j = 0; j < 2; ++j) {
            const int jj = w * 2 + j;              // 0..7
            const int r = jj >> 2, k4 = jj & 3;
            gld16(dst + jj * 512,
                  Wg + ((size_t)(s0 + r * 32 + c)) * 64 + k4 * 16 + hi * 8);
            gld16(dst + 4096 + jj * 512,
                  Vg + ((size_t)(r * 32 + c)) * T + s0 + k4 * 16 + hi * 8);
        }
    };

    stage(0, sLo);

    f32x16 o0 = {}, o1 = {};
    float lsum = 0.f;

    for (int i = 0; i < nT; ++i) {
        const int sb = sLo + i;
        if (i + 1 < nT) {
            stage((i + 1) & 1, sb + 1);
            asm volatile("s_waitcnt vmcnt(4)" ::: "memory");   // tile i ready
        } else {
            asm volatile("s_waitcnt vmcnt(0)" ::: "memory");
        }
        __builtin_amdgcn_s_barrier();

        if (sb <= myT) {           // false only for waves 0,1 at sb==2t+1
            const bf16* Wb = &ring[i & 1][0];
            const bf16* Vb = &ring[i & 1][4096];
            const int s0l = sb * 64 - sp * 512;    // slice-local s offset

            // S^T = W.K + b2 (C-init from b2 slice; rows = s)
            f32x16 sv0, sv1;
            #pragma unroll
            for (int qd = 0; qd < 4; ++qd) {
                float4 b4 = *(const float4*)&b2l[s0l + qd * 8 + 4 * hi];
                float4 b5 = *(const float4*)&b2l[s0l + 32 + qd * 8 + 4 * hi];
                sv0[4*qd] = b4.x; sv0[4*qd+1] = b4.y; sv0[4*qd+2] = b4.z; sv0[4*qd+3] = b4.w;
                sv1[4*qd] = b5.x; sv1[4*qd+1] = b5.y; sv1[4*qd+2] = b5.z; sv1[4*qd+3] = b5.w;
            }
            #pragma unroll
            for (int kst = 0; kst < 4; ++kst) {
                bf16x8 w0 = *(const bf16x8*)&Wb[kst * 512 + l * 8];
                bf16x8 w1 = *(const bf16x8*)&Wb[(4 + kst) * 512 + l * 8];
                sv0 = __builtin_amdgcn_mfma_f32_32x32x16_bf16(w0, kf[kst], sv0, 0, 0, 0);
                sv1 = __builtin_amdgcn_mfma_f32_32x32x16_bf16(w1, kf[kst], sv1, 0, 0, 0);
            }

            // exp (exact no-max), causal mask on diag tile, pack to bf16 pairs
            const bool diag = (sb == myT);
            const int qv = (w & 1) * 32 + c;       // q-pos within the 64-s diag pair
            u32 U0[8], U1[8];
            #pragma unroll
            for (int qd = 0; qd < 4; ++qd) {
                float e0[4], e1[4];
                #pragma unroll
                for (int k = 0; k < 4; ++k) {
                    const int sbase = qd * 8 + 4 * hi + k;
                    float ev0 = __expf(sv0[4*qd + k]);
                    float ev1 = __expf(sv1[4*qd + k]);
                    if (diag && sbase > qv)      ev0 = 0.f;
                    if (diag && sbase + 32 > qv) ev1 = 0.f;
                    lsum += ev0 + ev1;
                    e0[k] = ev0; e1[k] = ev1;
                }
                union { bf16x4 v; u32 uu[2]; } p0, p1;
                p0.v = {(bf16)e0[0], (bf16)e0[1], (bf16)e0[2], (bf16)e0[3]};
                p1.v = {(bf16)e1[0], (bf16)e1[1], (bf16)e1[2], (bf16)e1[3]};
                U0[2*qd] = p0.uu[0]; U0[2*qd+1] = p0.uu[1];
                U1[2*qd] = p1.uu[0]; U1[2*qd+1] = p1.uu[1];
            }

            // PV: assemble pa fragments in-register, O += P.V (v10/v11-verified)
            #define PV_TILE(Uarr, st)                                              \
            {                                                                      \
                _Pragma("unroll")                                                  \
                for (int kk = 0; kk < 2; ++kk) {                                   \
                    u32 A00 = Uarr[4*kk],   A01 = Uarr[4*kk+1];                    \
                    u32 A10 = Uarr[4*kk+2], A11 = Uarr[4*kk+3];                    \
                    u32 s00 = (u32)__shfl_xor((int)A00, 32);                       \
                    u32 s01 = (u32)__shfl_xor((int)A01, 32);                       \
                    u32 s10 = (u32)__shfl_xor((int)A10, 32);                       \
                    u32 s11 = (u32)__shfl_xor((int)A11, 32);                       \
                    union { u32 uu[4]; bf16x8 v; } pa;                             \
                    pa.uu[0] = hi ? s10 : A00;                                     \
                    pa.uu[1] = hi ? s11 : A01;                                     \
                    pa.uu[2] = hi ? A10 : s00;                                     \
                    pa.uu[3] = hi ? A11 : s01;                                     \
                    const int m = (st) * 2 + kk;                                   \
                    bf16x8 v0 = *(const bf16x8*)&Vb[m * 512 + l * 8];              \
                    bf16x8 v1 = *(const bf16x8*)&Vb[(4 + m) * 512 + l * 8];        \
                    o0 = __builtin_amdgcn_mfma_f32_32x32x16_bf16(pa.v, v0, o0, 0, 0, 0); \
                    o1 = __builtin_amdgcn_mfma_f32_32x32x16_bf16(pa.v, v1, o1, 0, 0, 0); \
                }                                                                  \
            }
            PV_TILE(U0, 0)
            PV_TILE(U1, 1)
            #undef PV_TILE
        }

        asm volatile("s_waitcnt lgkmcnt(0)" ::: "memory");
        __builtin_amdgcn_s_barrier();   // all reads done -> other buffer reusable
    }

    // epilogue: accumulate partials. lsum: lane's partial covers q=c over its
    // 32 of 64 s-rows; merge hi halves then one atomic per q.
    lsum += __shfl_xor(lsum, 32);
    if (hi == 0)
        atomicAdd(&Lacc[((size_t)(b * H + h)) * T + t0w + c], lsum);
    #pragma unroll
    for (int r = 0; r < 16; ++r) {
        const int q_ = (r & 3) + 8 * (r >> 2) + 4 * hi;
        float* p = Oacc + ((size_t)(b * T + t0w + q_)) * C + h * 64;
        atomicAdd(p + c,      o0[r]);
        atomicAdd(p + c + 32, o1[r]);
    }
}

// normalize: Ob = bf16(Oacc / Lacc[row,head])
__global__ __launch_bounds__(256) void attn_norm_k(const float* __restrict__ Oacc,
                                                   const float* __restrict__ Lacc,
                                                   bf16* __restrict__ Ob)
{
    const int i = (blockIdx.x * blockDim.x + threadIdx.x) * 4;   // over R*C
    const int row = i >> 10;            // b*T + tq   (C = 1024)
    const int ch = i & 1023;
    const int h = ch >> 6;
    const int b = row >> 11, tq = row & 2047;   // T = 2048
    const float inv = 1.f / Lacc[((size_t)(b * 16 + h)) * 2048 + tq];
    float4 v = *(const float4*)(Oacc + i);
    bf16x4 o = {(bf16)(v.x * inv), (bf16)(v.y * inv),
                (bf16)(v.z * inv), (bf16)(v.w * inv)};
    *(bf16x4*)(Ob + i) = o;
}

extern "C" void kernel_launch(void* const* d_in, const int* in_sizes, int n_in,
                              void* d_out, int out_size, void* d_ws, size_t ws_size,
                              hipStream_t stream) {
    const float* x       = (const float*)d_in[0];
    const float* w1_w    = (const float*)d_in[1];
    const float* w1_b    = (const float*)d_in[2];
    const float* w2      = (const float*)d_in[3];
    const float* b2      = (const float*)d_in[4];
    const float* value_w = (const float*)d_in[5];
    const float* value_b = (const float*)d_in[6];
    const float* proj_w  = (const float*)d_in[7];
    const float* proj_b  = (const float*)d_in[8];

    const int B = 2, T = 2048, C = 1024, H = 16, M = 2048;
    const int R = B * T;   // 4096

    bf16* xb  = (bf16*)d_ws;                  // [R][C]
    bf16* w1b = xb  + (size_t)R * C;          // [C][C]   } contiguous ->
    bf16* vwb = w1b + (size_t)C * C;          // [C][C]   } fused B [2C][C]
    bf16* w2t = vwb + (size_t)C * C;          // [H][M][64]
    bf16* pwb = w2t + (size_t)H * M * 64;     // [C][C]
    bf16* Kb  = pwb + (size_t)C * C;          // [R][C]
    bf16* VTb = Kb  + (size_t)R * C;          // [B][C][T]
    bf16* Ob  = VTb + (size_t)R * C;          // [R][C]
    float* Oacc = (float*)(Ob + (size_t)R * C);   // [R][C] f32 (16 MB)
    float* Lacc = Oacc + (size_t)R * C;           // [B*H*T] f32 (256 KB)
    // total ws use ~58.5 MB

    // zero the accumulators (ws is NOT re-poisoned between replays, so this
    // must happen every call)
    hipMemsetAsync(Oacc, 0, ((size_t)R * C + (size_t)B * H * T) * sizeof(float), stream);

    cast_bf16_k<<<1024, 256, 0, stream>>>(x, xb, R * C);
    cast3_bf16_k<<<512, 256, 0, stream>>>(w1_w, w1b, value_w, vwb, proj_w, pwb, C * C);
    w2_transpose_k<<<dim3(M / 64, H), 256, 0, stream>>>(w2, w2t, M);

    // fused K/V GEMM: N = 2C, B-operand = [w1b ; vwb]
    gemm_bf16_k<<<dim3(2 * C / 128, R / 128), 256, 0, stream>>>(
        xb, w1b, w1_b, value_b, nullptr, Kb, VTb, R, 2 * C, C, 1, C);

    synth_attn_v12<<<dim3(1280), 256, 0, stream>>>(Kb, VTb, w2t, b2, Oacc, Lacc);
    attn_norm_k<<<dim3(R * C / 1024), 256, 0, stream>>>(Oacc, Lacc, Ob);

    gemm_bf16_k<<<dim3(C / 128, R / 128), 256, 0, stream>>>(
        Ob, pwb, proj_b, nullptr, (float*)d_out, nullptr, nullptr, R, C, C, 0, C);
}

// Round 13
// 99.346 us; speedup vs baseline: 1.2988x; 1.2988x over previous
//
#include <hip/hip_runtime.h>
#include <math.h>
#include <stdint.h>

typedef __bf16 bf16;
typedef __bf16 bf16x8 __attribute__((ext_vector_type(8)));
typedef __bf16 bf16x4 __attribute__((ext_vector_type(4)));
typedef float f32x4 __attribute__((ext_vector_type(4)));
typedef unsigned int u32;

// element index into a [rows][64] bf16 tile, XOR-swizzled in 16B (8-elem) chunks
__device__ __forceinline__ int swz(int row, int chunk) {
    return row * 64 + ((chunk ^ (row & 7)) << 3);
}

// async 16B global->LDS; lds must be wave-uniform base (HW adds lane*16)
__device__ __forceinline__ void gld16(void* lds, const void* g) {
    __builtin_amdgcn_global_load_lds(
        (const __attribute__((address_space(1))) u32*)g,
        (__attribute__((address_space(3))) u32*)lds, 16, 0, 0);
}

// 8-wave staging of a 64x64 bf16 tile: each wave issues ONE gld16 covering 8
// rows. Linear LDS dest + inverse-XOR on the SOURCE chunk so swizzled reads
// see LDS[row][chunk^(row&7)] == src[row][chunk].
__device__ __forceinline__ void stage8(bf16* dst, const bf16* src, size_t srcStride,
                                       int w, int l) {
    const int br = w * 8;
    const int r = br + (l >> 3);
    const int gs = (l & 7) ^ (r & 7);
    gld16(dst + br * 64, src + (size_t)r * srcStride + gs * 8);
}

// ONE prep launch: blocks [0,512) transpose w2 -> w2t bf16; [512,1024) cast the
// three square weights; [1024,2048) cast x. All branches block-uniform.
__global__ __launch_bounds__(256) void prep_all_k(const float* __restrict__ x,  bf16* __restrict__ xb,
                                                  const float* __restrict__ w1_w, bf16* __restrict__ w1b,
                                                  const float* __restrict__ value_w, bf16* __restrict__ vwb,
                                                  const float* __restrict__ proj_w, bf16* __restrict__ pwb,
                                                  const float* __restrict__ w2, bf16* __restrict__ w2t,
                                                  int nx, int nw)
{
    const int bx = blockIdx.x;
    const int t = threadIdx.x;
    if (bx < 512) {
        constexpr int M = 2048;
        __shared__ float Tf[64][65];
        const int h = bx >> 5, m0 = (bx & 31) * 64;
        {
            const int dr = t >> 4, c4 = (t & 15) * 4;
            #pragma unroll
            for (int it = 0; it < 4; ++it) {
                const int d = dr + it * 16;
                float4 v = *(const float4*)(w2 + ((size_t)h * 64 + d) * M + m0 + c4);
                Tf[d][c4] = v.x; Tf[d][c4 + 1] = v.y; Tf[d][c4 + 2] = v.z; Tf[d][c4 + 3] = v.w;
            }
        }
        __syncthreads();
        const int m = t >> 2;
        #pragma unroll
        for (int it = 0; it < 2; ++it) {
            const int ch = (t & 3) + it * 4;
            bf16x8 o;
            #pragma unroll
            for (int j = 0; j < 8; ++j) o[j] = (bf16)Tf[ch * 8 + j][m];
            *(bf16x8*)(w2t + ((size_t)h * M + m0 + m) * 64 + ch * 8) = o;
        }
    } else if (bx < 1024) {
        const int stride = 512 * 256 * 4;
        for (int i = ((bx - 512) * 256 + t) * 4; i < nw; i += stride) {
            float4 v0 = *(const float4*)(w1_w + i);
            float4 v1 = *(const float4*)(value_w + i);
            float4 v2 = *(const float4*)(proj_w + i);
            bf16x4 o0 = {(bf16)v0.x, (bf16)v0.y, (bf16)v0.z, (bf16)v0.w};
            bf16x4 o1 = {(bf16)v1.x, (bf16)v1.y, (bf16)v1.z, (bf16)v1.w};
            bf16x4 o2 = {(bf16)v2.x, (bf16)v2.y, (bf16)v2.z, (bf16)v2.w};
            *(bf16x4*)(w1b + i) = o0;
            *(bf16x4*)(vwb + i) = o1;
            *(bf16x4*)(pwb + i) = o2;
        }
    } else {
        const int stride = 1024 * 256 * 4;
        for (int i = ((bx - 1024) * 256 + t) * 4; i < nx; i += stride) {
            float4 v = *(const float4*)(x + i);
            bf16x4 o = {(bf16)v.x, (bf16)v.y, (bf16)v.z, (bf16)v.w};
            *(bf16x4*)(xb + i) = o;
        }
    }
}

// 128x128x64 bf16 MFMA GEMM (R9-verified: counted-vmcnt double buffer).
__global__ __launch_bounds__(256, 2) void gemm_bf16_k(const bf16* __restrict__ A,
                                                   const bf16* __restrict__ Bw,
                                                   const float* __restrict__ bias,
                                                   const float* __restrict__ bias2,
                                                   float* __restrict__ C0,
                                                   bf16* __restrict__ CK,
                                                   bf16* __restrict__ CV,
                                                   int M, int N, int K, int mode, int Ns)
{
    __shared__ __align__(16) bf16 As[2][128 * 64];
    __shared__ __align__(16) bf16 Bs[2][128 * 64];
    const int tid = threadIdx.x;
    const int w = tid >> 6, l = tid & 63;
    const int wr = w >> 1, wc = w & 1;
    const int lc = l & 15, lg = l >> 4;
    const int row0 = blockIdx.y * 128, col0 = blockIdx.x * 128;

    f32x4 acc[4][4] = {};

    const int nk = K >> 6;
    auto issue = [&](int buf, int k0) {
        #pragma unroll
        for (int i = 0; i < 4; ++i) {
            const int br = (w * 4 + i) * 8;
            const int r = br + (l >> 3);
            const int gs = (l & 7) ^ (r & 7);
            gld16(&As[buf][br * 64], A  + (size_t)(row0 + r) * K + k0 + gs * 8);
            gld16(&Bs[buf][br * 64], Bw + (size_t)(col0 + r) * K + k0 + gs * 8);
        }
    };

    issue(0, 0);
    int cur = 0;
    for (int kt = 0; kt < nk; ++kt) {
        if (kt + 1 < nk) {
            issue(cur ^ 1, (kt + 1) << 6);
            asm volatile("s_waitcnt vmcnt(8)" ::: "memory");
        } else {
            asm volatile("s_waitcnt vmcnt(0)" ::: "memory");
        }
        __builtin_amdgcn_s_barrier();
        #pragma unroll
        for (int ks = 0; ks < 2; ++ks) {
            bf16x8 af[4], bfv[4];
            #pragma unroll
            for (int i = 0; i < 4; ++i) {
                af[i]  = *(const bf16x8*)&As[cur][swz(wr * 64 + i * 16 + lc, ks * 4 + lg)];
                bfv[i] = *(const bf16x8*)&Bs[cur][swz(wc * 64 + i * 16 + lc, ks * 4 + lg)];
            }
            #pragma unroll
            for (int mi = 0; mi < 4; ++mi)
                #pragma unroll
                for (int ni = 0; ni < 4; ++ni)
                    acc[mi][ni] = __builtin_amdgcn_mfma_f32_16x16x32_bf16(af[mi], bfv[ni], acc[mi][ni], 0, 0, 0);
        }
        asm volatile("s_waitcnt lgkmcnt(0)" ::: "memory");
        __builtin_amdgcn_s_barrier();
        cur ^= 1;
    }

    #pragma unroll
    for (int ni = 0; ni < 4; ++ni) {
        const int col = col0 + wc * 64 + ni * 16 + lc;
        #pragma unroll
        for (int mi = 0; mi < 4; ++mi) {
            const int rowb = row0 + wr * 64 + mi * 16 + lg * 4;
            f32x4 v = acc[mi][ni];
            if (mode == 0) {
                const float bv = bias[col];
                #pragma unroll
                for (int r = 0; r < 4; ++r)
                    C0[(size_t)(rowb + r) * N + col] = v[r] + bv;
            } else if (col < Ns) {
                const float bv = bias[col];
                #pragma unroll
                for (int r = 0; r < 4; ++r)
                    CK[(size_t)(rowb + r) * Ns + col] = (bf16)fmaxf(v[r] + bv, 0.f);
            } else {
                const float bv = bias2[col - Ns];
                const int b = rowb >> 11, tt = rowb & 2047;   // T = 2048
                bf16x4 o = {(bf16)(v[0] + bv), (bf16)(v[1] + bv),
                            (bf16)(v[2] + bv), (bf16)(v[3] + bv)};
                *(bf16x4*)(CV + ((size_t)b * Ns + (col - Ns)) * 2048 + tt) = o;
            }
        }
    }
}

// one SWAPPED QK -> softmax -> PV step on the staged 64x64 W/V tile.
// S^T = mfma(A=W^T s-rows, B=K q-cols): sv[st][r] = S[s=st*16+lg*4+r][q=wq*16+lc]
//   -> lane's 4 values per st are 4 CONSECUTIVE s for one q: P write is a
//      single bf16x4 (ds_write_b64) per st instead of 16 scalar b16 writes.
// P stored [q=16][s=64] (swizzled) so PV A-frag read stays ds_read_b128.
__device__ __forceinline__ void tile_step(bf16x8 kf0, bf16x8 kf1,
                                          const bf16* Wb, const bf16* Vb,
                                          bf16* Pw, const float* b2l, int s0,
                                          f32x4 (&acc)[4], float& lsum,
                                          bool diag, int lc, int lg, int wq)
{
    // S^T = W . K + b2 (bias varies along s = MFMA rows = f32x4 elements)
    f32x4 sv[4];
    #pragma unroll
    for (int st = 0; st < 4; ++st) {
        const float4 b4 = *(const float4*)&b2l[s0 + st * 16 + lg * 4];
        sv[st] = {b4.x, b4.y, b4.z, b4.w};
    }
    #pragma unroll
    for (int st = 0; st < 4; ++st) {
        bf16x8 wb0 = *(const bf16x8*)&Wb[swz(st * 16 + lc, lg)];
        bf16x8 wb1 = *(const bf16x8*)&Wb[swz(st * 16 + lc, 4 + lg)];
        sv[st] = __builtin_amdgcn_mfma_f32_16x16x32_bf16(wb0, kf0, sv[st], 0, 0, 0);
        sv[st] = __builtin_amdgcn_mfma_f32_16x16x32_bf16(wb1, kf1, sv[st], 0, 0, 0);
    }
    // exp (exact, no max: |S| bounded small), causal mask, packed P write
    const int qv = wq * 16 + lc;
    #pragma unroll
    for (int st = 0; st < 4; ++st) {
        float e[4];
        #pragma unroll
        for (int r = 0; r < 4; ++r) {
            const int sidx = st * 16 + lg * 4 + r;
            float ev = __expf(sv[st][r]);
            if (diag && sidx > qv) ev = 0.f;
            e[r] = ev;
            lsum += ev;
        }
        bf16x4 pw = {(bf16)e[0], (bf16)e[1], (bf16)e[2], (bf16)e[3]};
        const int chunk = st * 2 + (lg >> 1);
        *(bf16x4*)&Pw[lc * 64 + ((chunk ^ (lc & 7)) << 3) + ((lg & 1) << 2)] = pw;
    }
    // O += P . V
    #pragma unroll
    for (int ks = 0; ks < 2; ++ks) {
        bf16x8 pf = *(const bf16x8*)&Pw[swz(lc, ks * 4 + lg)];
        #pragma unroll
        for (int dt = 0; dt < 4; ++dt) {
            bf16x8 vv = *(const bf16x8*)&Vb[swz(dt * 16 + lc, ks * 4 + lg)];
            acc[dt] = __builtin_amdgcn_mfma_f32_16x16x32_bf16(pf, vv, acc[dt], 0, 0, 0);
        }
    }
}

// v9 (R9-verified, best measured): 512 threads; waves 0-3 -> q-tile 31-j,
// waves 4-7 -> q-tile j, shared 3-buffer W/V ring, counted vmcnt, b2 in LDS,
// swapped-QK packed-P tile_step.
__global__ __launch_bounds__(512, 4) void synth_attn_v9(const bf16* __restrict__ Kb,
                                                        const bf16* __restrict__ VT,
                                                        const bf16* __restrict__ w2t,
                                                        const float* __restrict__ b2,
                                                        bf16* __restrict__ Ob)
{
    constexpr int T = 2048, C = 1024, M = 2048;
    __shared__ __align__(16) bf16 Wl[3][64 * 64];
    __shared__ __align__(16) bf16 Vl[3][64 * 64];
    __shared__ __align__(16) bf16 Pl[8][16 * 64];
    __shared__ float b2l[M];
    const int tid = threadIdx.x;
    const int w = tid >> 6, l = tid & 63;
    const int lc = l & 15, lg = l >> 4;
    const int wq = w & 3, wt = w >> 2;

    const int bx = blockIdx.x;
    const int j = bx & 15;
    const int bh = bx >> 4;
    const int h = bh & 15, b = bh >> 4;
    const int tA = j, tB = 31 - j;
    const int myT = wt ? tA : tB;
    const int t0 = myT * 64;

    // b2 -> LDS (512 threads x 4 floats = 2048)
    *(float4*)&b2l[tid * 4] = *(const float4*)(b2 + tid * 4);
    __syncthreads();

    const bf16* Wgt = w2t + (size_t)h * M * 64;            // [s][64] rows
    const bf16* Vgt = VT + ((size_t)b * C + h * 64) * T;   // [d][T] rows
    bf16* Pw = &Pl[w][0];

    // K fragments for this wave's 16 q-rows (B-operand of swapped QK)
    const bf16* Kg = Kb + (size_t)(b * T + t0 + wq * 16 + lc) * C + h * 64;
    const bf16x8 kf0 = *(const bf16x8*)(Kg + lg * 8);
    const bf16x8 kf1 = *(const bf16x8*)(Kg + 32 + lg * 8);

    // prologue: stage tiles 0 and 1 (tB >= 16, both exist)
    stage8(&Wl[0][0], Wgt, 64, w, l);
    stage8(&Vl[0][0], Vgt, T, w, l);
    stage8(&Wl[1][0], Wgt + (size_t)64 * 64, 64, w, l);
    stage8(&Vl[1][0], Vgt + 64, T, w, l);

    f32x4 acc[4] = {};
    float lsum = 0.f;

    int cur = 0;
    for (int sb = 0; sb <= tB; ++sb) {
        const int s0 = sb * 64;
        // my 2 loads for tile sb done; tile sb+1's 2 may stay in flight
        if (sb < tB) asm volatile("s_waitcnt vmcnt(2)" ::: "memory");
        else         asm volatile("s_waitcnt vmcnt(0)" ::: "memory");
        __builtin_amdgcn_s_barrier();

        if (sb <= myT)
            tile_step(kf0, kf1, &Wl[cur][0], &Vl[cur][0], Pw, b2l, s0,
                      acc, lsum, sb == myT, lc, lg, wq);

        // stage tile sb+2 into buf (sb+2)%3: its readers crossed this barrier
        if (sb + 2 <= tB) {
            int nx = cur + 2; if (nx >= 3) nx -= 3;
            stage8(&Wl[nx][0], Wgt + (size_t)(s0 + 128) * 64, 64, w, l);
            stage8(&Vl[nx][0], Vgt + (s0 + 128), T, w, l);
        }
        if (++cur == 3) cur = 0;
    }

    // epilogue: lane's lsum is the partial row-sum for q=wq*16+lc; reduce over
    // the 4 lanes sharing lc (xor 16/32), then redistribute to the acc layout
    // (q = lg*4+r) via shfl from lane q.
    float ls = lsum;
    ls += __shfl_xor(ls, 16);
    ls += __shfl_xor(ls, 32);
    #pragma unroll
    for (int r = 0; r < 4; ++r) {
        const float inv = 1.f / __shfl(ls, lg * 4 + r);
        bf16* dst = Ob + (size_t)(b * T + t0 + wq * 16 + lg * 4 + r) * C + h * 64;
        #pragma unroll
        for (int dt = 0; dt < 4; ++dt)
            dst[dt * 16 + lc] = (bf16)(acc[dt][r] * inv);
    }
}

extern "C" void kernel_launch(void* const* d_in, const int* in_sizes, int n_in,
                              void* d_out, int out_size, void* d_ws, size_t ws_size,
                              hipStream_t stream) {
    const float* x       = (const float*)d_in[0];
    const float* w1_w    = (const float*)d_in[1];
    const float* w1_b    = (const float*)d_in[2];
    const float* w2      = (const float*)d_in[3];
    const float* b2      = (const float*)d_in[4];
    const float* value_w = (const float*)d_in[5];
    const float* value_b = (const float*)d_in[6];
    const float* proj_w  = (const float*)d_in[7];
    const float* proj_b  = (const float*)d_in[8];

    const int B = 2, T = 2048, C = 1024, H = 16, M = 2048;
    const int R = B * T;   // 4096

    bf16* xb  = (bf16*)d_ws;                  // [R][C]
    bf16* w1b = xb  + (size_t)R * C;          // [C][C]   } contiguous ->
    bf16* vwb = w1b + (size_t)C * C;          // [C][C]   } fused B [2C][C]
    bf16* w2t = vwb + (size_t)C * C;          // [H][M][64]
    bf16* pwb = w2t + (size_t)H * M * 64;     // [C][C]
    bf16* Kb  = pwb + (size_t)C * C;          // [R][C]
    bf16* VTb = Kb  + (size_t)R * C;          // [B][C][T]
    bf16* Ob  = VTb + (size_t)R * C;          // [R][C]    total 42 MB

    // one prep launch: w2 transpose + 3 weight casts + x cast
    prep_all_k<<<2048, 256, 0, stream>>>(x, xb, w1_w, w1b, value_w, vwb,
                                         proj_w, pwb, w2, w2t, R * C, C * C);

    // fused K/V GEMM: N = 2C, B-operand = [w1b ; vwb]
    gemm_bf16_k<<<dim3(2 * C / 128, R / 128), 256, 0, stream>>>(
        xb, w1b, w1_b, value_b, nullptr, Kb, VTb, R, 2 * C, C, 1, C);

    synth_attn_v9<<<dim3(512), 512, 0, stream>>>(Kb, VTb, w2t, b2, Ob);

    gemm_bf16_k<<<dim3(C / 128, R / 128), 256, 0, stream>>>(
        Ob, pwb, proj_b, nullptr, (float*)d_out, nullptr, nullptr, R, C, C, 0, C);
}